// Round 5
// baseline (457.676 us; speedup 1.0000x reference)
//
#include <hip/hip_runtime.h>
#include <math.h>

#define B_   32768
#define K_   1024
#define NIT  32          // K-loop iterations (BK = 32)
#define CPT  512         // 16B chunks per operand per iter-tile: 128 rows x 4 col-chunks

typedef __bf16 bf16x8 __attribute__((ext_vector_type(8)));
typedef float  f32x4  __attribute__((ext_vector_type(4)));
typedef float  f4     __attribute__((ext_vector_type(4)));
typedef float  f2     __attribute__((ext_vector_type(2)));
typedef unsigned short us8 __attribute__((ext_vector_type(8)));

__device__ __forceinline__ unsigned short f2bf(float f) {
    unsigned u = __float_as_uint(f);
    u += 0x7fffu + ((u >> 16) & 1u);   // round-to-nearest-even
    return (unsigned short)(u >> 16);
}
__device__ __forceinline__ float sigm(float x) {
    return 1.f / (1.f + __expf(-x));
}
__device__ __forceinline__ float tanh_fast(float x) {
    return 1.f - 2.f / (__expf(2.f * x) + 1.f);
}
// async global->LDS, 16B per lane. LDS dest = wave-uniform base + lane*16.
__device__ __forceinline__ void gload16(const unsigned short* g, unsigned short* l) {
    __builtin_amdgcn_global_load_lds(
        (const __attribute__((address_space(1))) unsigned int*)g,
        (__attribute__((address_space(3))) unsigned int*)l, 16, 0, 0);
}

// ---------------- prep: pack x||h -> XHt, transpose-pack weights -> Wtt, zero accL ----
// Role by blockIdx.x (all branches block-uniform):
//   [0, 16384)        : XHt chunks (tiled + pre-swizzled, as round 4)
//   [16384, 18432)    : Wtt tiles  (tiled + pre-swizzled, as round 4)
//   [18432, 18448)    : zero the 256 KB logit accumulator
__global__ __launch_bounds__(256) void prep_kernel(
    const float* __restrict__ x, const float* __restrict__ h,
    const float* __restrict__ Uf, const float* __restrict__ Vf,
    const float* __restrict__ Ui, const float* __restrict__ Vi,
    const float* __restrict__ Uo, const float* __restrict__ Vo,
    const float* __restrict__ Uc, const float* __restrict__ Vc,
    unsigned short* __restrict__ XHt, unsigned short* __restrict__ Wtt,
    float* __restrict__ accL) {
    __shared__ float tile[32][33];
    const int b = blockIdx.x;
    const int t = threadIdx.x;
    if (b < 16384) {
        // XHt chunk p = (mb*32 + it)*512 + r*4 + gcx holds 8 bf16 of
        // XH[mb*128 + r][it*32 + (gcx ^ ((r>>1)&3))*8 .. +7]  (k<512 -> x, else h)
        unsigned p   = b * 256u + t;
        unsigned c   = p & 511u;
        unsigned T   = p >> 9;
        unsigned it  = T & 31u;
        unsigned mb  = T >> 5;
        unsigned r   = c >> 2;
        unsigned gcx = c & 3u;
        unsigned gc  = gcx ^ ((r >> 1) & 3u);
        unsigned m   = mb * 128u + r;
        unsigned k   = it * 32u + gc * 8u;
        const float* src = (k < 512u) ? (x + (size_t)m * 512u + k)
                                      : (h + (size_t)m * 512u + (k - 512u));
        f4 v0 = *(const f4*)src;
        f4 v1 = *(const f4*)(src + 4);
        us8 o;
        o[0] = f2bf(v0.x); o[1] = f2bf(v0.y); o[2] = f2bf(v0.z); o[3] = f2bf(v0.w);
        o[4] = f2bf(v1.x); o[5] = f2bf(v1.y); o[6] = f2bf(v1.z); o[7] = f2bf(v1.w);
        *(us8*)(XHt + (size_t)p * 8u) = o;
    } else if (b < 18432) {
        // Wtt chunk p = (jb*32 + it)*512 + r*4 + gcx, r = g*32 + jj, holds
        // W[row = g*512 + jb*32 + jj][k = it*32 + (gcx^((jj>>1)&3))*8 .. +7]
        const float* srcs[8] = {Uf, Vf, Ui, Vi, Uo, Vo, Uc, Vc};
        const int idx = b - 16384;           // 0..2047
        const int w   = idx >> 8;            // 0..7 : (g, isV)
        const int kw  = (idx >> 4) & 15;     // 32-k window within the 512
        const int jb  = idx & 15;
        const float* src = srcs[w];
        const int g   = w >> 1;
        const int isV = w & 1;
        const int j0  = jb * 32;
        const int k0  = kw * 32;
        const int it  = isV * 16 + kw;
        #pragma unroll
        for (int p = 0; p < 4; ++p) {
            int kl = p * 8 + (t >> 5);
            int jj = t & 31;
            tile[kl][jj] = src[(size_t)(k0 + kl) * 512 + j0 + jj];   // coalesced over j
        }
        __syncthreads();
        if (t < 128) {
            const int jj  = t >> 2;
            const int gcx = t & 3;
            const int gc  = gcx ^ ((jj >> 1) & 3);
            const int r   = g * 32 + jj;
            us8 o;
            #pragma unroll
            for (int u = 0; u < 8; ++u) o[u] = f2bf(tile[gc * 8 + u][jj]);
            *(us8*)(Wtt + ((size_t)(jb * 32 + it) * 512 + r * 4 + gcx) * 8) = o;
        }
    } else {
        // zero accL: 65536 floats; 16 blocks x 256 threads x 16B
        const int i = (b - 18432) * 256 + t;
        f4 z = {0.f, 0.f, 0.f, 0.f};
        *(f4*)(accL + (size_t)i * 4) = z;
    }
}

// ---------------- fused GEMM + LSTM gates + partial logits ----------------
// 128x128 output tile (128 rows x {4 gates x 32 j}), BK=32, 4 waves, 16x16x32 MFMA.
// 2-phase double-buffered LDS, global_load_lds staging of tile t+1 issued BEFORE
// computing tile t, one barrier per iteration. Sources tiled+pre-swizzled so LDS
// stays linear and fragment ds_read_b128 are conflict-free (validated round 4:
// 178us, MfmaUtil 35%, FETCH 204MB, WRITE = exact output bytes).
// Epilogue: gates in-register -> h/c tiles through LDS as full 128B lines; while
// the h tile sits in LDS, 2 threads/row dot it with Wout and atomicAdd partial
// logits (removes the separate logits kernel and its 64MB re-read).
__global__ __launch_bounds__(256, 2) void gemm_fused_kernel(
    const unsigned short* __restrict__ XHt,
    const unsigned short* __restrict__ Wtt,
    const float* __restrict__ cell,
    const float* __restrict__ bfp, const float* __restrict__ bip,
    const float* __restrict__ bop, const float* __restrict__ bcp,
    const float* __restrict__ Wout,
    float* __restrict__ accL,
    float* __restrict__ out) {
    __shared__ __attribute__((aligned(16))) unsigned short lds[2 * 2 * CPT * 8];  // 32 KB
    const int t    = threadIdx.x;
    const int lane = t & 63;
    const int w    = t >> 6;
    const int wm   = w >> 1;
    const int wn   = w & 1;

    // XCD swizzle (bijective, 4096 % 8 == 0): each XCD gets contiguous m-strips
    // with jb fastest -> XH strip reuse in that XCD's L2.
    const unsigned lin = blockIdx.y * gridDim.x + blockIdx.x;
    const unsigned wg  = (lin & 7u) * 512u + (lin >> 3);
    const int jb = (int)(wg & 15u);
    const int mb = (int)(wg >> 4);
    const int jblk = jb * 32;
    const int m0   = mb * 128;

    f32x4 acc[4][4];
    #pragma unroll
    for (int i = 0; i < 4; ++i)
        #pragma unroll
        for (int j = 0; j < 4; ++j) { f32x4 z = {0.f, 0.f, 0.f, 0.f}; acc[i][j] = z; }

    const unsigned short* aS = XHt + (size_t)mb * (NIT * CPT * 8);
    const unsigned short* bS = Wtt + (size_t)jb * (NIT * CPT * 8);
    const int cw = w * 64;                 // wave's chunk base within a 256-chunk group

    auto stage = [&](int buf, int it) {
        const unsigned short* a = aS + (size_t)it * (CPT * 8);
        const unsigned short* b = bS + (size_t)it * (CPT * 8);
        unsigned short* lA = lds + buf * (2 * CPT * 8);
        unsigned short* lB = lA + CPT * 8;
        gload16(a + (size_t)(cw + lane) * 8,       lA + cw * 8);
        gload16(a + (size_t)(cw + lane + 256) * 8, lA + (cw + 256) * 8);
        gload16(b + (size_t)(cw + lane) * 8,       lB + cw * 8);
        gload16(b + (size_t)(cw + lane + 256) * 8, lB + (cw + 256) * 8);
    };

    const int q   = lane & 15;
    const int ccf = lane >> 4;                  // k-chunk of the fragment
    const int swz = ccf ^ ((q >> 1) & 3);       // (r>>1)&3 == (q>>1)&3 for all our rows

    auto compute = [&](int buf) {
        const unsigned short* lA = lds + buf * (2 * CPT * 8);
        const unsigned short* lB = lA + CPT * 8;
        bf16x8 af[4], bfr[4];
        #pragma unroll
        for (int mt = 0; mt < 4; ++mt)
            af[mt] = *(const bf16x8*)(lA + ((wm * 64 + mt * 16 + q) * 4 + swz) * 8);
        #pragma unroll
        for (int nt = 0; nt < 4; ++nt)
            bfr[nt] = *(const bf16x8*)(lB + ((nt * 32 + wn * 16 + q) * 4 + swz) * 8);
        #pragma unroll
        for (int mt = 0; mt < 4; ++mt)
            #pragma unroll
            for (int nt = 0; nt < 4; ++nt)
                acc[mt][nt] = __builtin_amdgcn_mfma_f32_16x16x32_bf16(af[mt], bfr[nt], acc[mt][nt], 0, 0, 0);
    };

    stage(0, 0);
    __syncthreads();                        // implicit vmcnt(0): buf0 ready
    for (int it = 0; it < NIT; it += 2) {
        if (it + 1 < NIT) stage(1, it + 1); // in flight through compute(0)
        compute(0);
        __syncthreads();                    // drains stage(1,..); readers of buf0 done
        if (it + 2 < NIT) stage(0, it + 2); // in flight through compute(1)
        compute(1);
        __syncthreads();
    }

    // ---- fused epilogue ----
    // C/D layout: col = lane&15 (-> local j), row = (lane>>4)*4 + rr; nt = gate.
    const int jc  = wn * 16 + q;               // local col in [0,32)
    const int j   = jblk + jc;                 // global hidden idx
    const float bF = bfp[j], bI = bip[j], bO = bop[j], bC = bcp[j];
    const int rlb = wm * 64 + ((lane >> 4) << 2);
    float hnv[16], cnv[16];
    #pragma unroll
    for (int mt = 0; mt < 4; ++mt) {
        #pragma unroll
        for (int rr = 0; rr < 4; ++rr) {
            const int row = m0 + rlb + mt * 16 + rr;
            const float sf = sigm(acc[mt][0][rr] + bF);
            const float si = sigm(acc[mt][1][rr] + bI);
            const float so = sigm(acc[mt][2][rr] + bO);
            const float ch = tanh_fast(acc[mt][3][rr] + bC);
            const float cold = cell[(size_t)row * 512 + j];
            const float cn = sf * cold + si * ch;
            cnv[mt * 4 + rr] = cn;
            hnv[mt * 4 + rr] = so * tanh_fast(cn);
        }
    }

    // LDS-staged full-128B-line stores. 128 x 36-padded f32 tile = 18.4 KB.
    float* eb   = (float*)lds;
    float* hout = out + 65536;
    float* cout = out + 65536 + 16777216;
    #pragma unroll
    for (int mt = 0; mt < 4; ++mt)
        #pragma unroll
        for (int rr = 0; rr < 4; ++rr)
            eb[(rlb + mt * 16 + rr) * 36 + jc] = hnv[mt * 4 + rr];
    __syncthreads();
    #pragma unroll
    for (int i = 0; i < 4; ++i) {   // each wave-instr: 64 lanes x 16B = 8 full lines
        const int r  = i * 32 + (t >> 3);
        const int c4 = (t & 7) * 4;
        f4 v = *(const f4*)(eb + r * 36 + c4);
        *(f4*)(hout + (size_t)(m0 + r) * 512 + jblk + c4) = v;
    }
    // partial logits from the h tile still in LDS: 2 threads/row, 16 cols each
    {
        const int r    = t >> 1;           // 0..127
        const int half = t & 1;
        const int c0   = half * 16;
        float p0 = 0.f, p1 = 0.f;
        #pragma unroll
        for (int i = 0; i < 16; ++i) {
            const float hv = eb[r * 36 + c0 + i];
            const float w0 = Wout[(jblk + c0 + i) * 2 + 0];
            const float w1 = Wout[(jblk + c0 + i) * 2 + 1];
            p0 += hv * w0;
            p1 += hv * w1;
        }
        p0 += __shfl_xor(p0, 1);           // combine the two halves of the row
        p1 += __shfl_xor(p1, 1);
        if (half == 0) {
            atomicAdd(&accL[(size_t)(m0 + r) * 2 + 0], p0);
            atomicAdd(&accL[(size_t)(m0 + r) * 2 + 1], p1);
        }
    }
    __syncthreads();
    #pragma unroll
    for (int mt = 0; mt < 4; ++mt)
        #pragma unroll
        for (int rr = 0; rr < 4; ++rr)
            eb[(rlb + mt * 16 + rr) * 36 + jc] = cnv[mt * 4 + rr];
    __syncthreads();
    #pragma unroll
    for (int i = 0; i < 4; ++i) {
        const int r  = i * 32 + (t >> 3);
        const int c4 = (t & 7) * 4;
        f4 v = *(const f4*)(eb + r * 36 + c4);
        *(f4*)(cout + (size_t)(m0 + r) * 512 + jblk + c4) = v;
    }
}

// ---------------- finale: softmax over accumulated logits ----------------
__global__ __launch_bounds__(256) void finale_kernel(const float* __restrict__ accL,
                                                     const float* __restrict__ bout,
                                                     float* __restrict__ out) {
    const int row = blockIdx.x * 256 + threadIdx.x;
    f2 a = *(const f2*)(accL + (size_t)row * 2);
    float l0 = a.x + bout[0], l1 = a.y + bout[1];
    float mx = fmaxf(l0, l1);
    float e0 = __expf(l0 - mx), e1 = __expf(l1 - mx);
    float s  = e0 + e1;
    f2 r; r.x = e0 / s; r.y = e1 / s;
    *(f2*)(out + (size_t)row * 2) = r;
}

// ---------------- fallback (only if workspace is too small): naive fp32 ----------------
__global__ __launch_bounds__(256) void fallback_kernel(
    const float* __restrict__ x, const float* __restrict__ h, const float* __restrict__ cell,
    const float* __restrict__ Uf, const float* __restrict__ Vf, const float* __restrict__ bfp,
    const float* __restrict__ Ui, const float* __restrict__ Vi, const float* __restrict__ bip,
    const float* __restrict__ Uo, const float* __restrict__ Vo, const float* __restrict__ bop,
    const float* __restrict__ Uc, const float* __restrict__ Vc, const float* __restrict__ bcp,
    const float* __restrict__ Wout, const float* __restrict__ bout, float* __restrict__ out) {
    const int row = blockIdx.x;
    const int t   = threadIdx.x;
    __shared__ float xs[512], hs[512];
    xs[t]       = x[(size_t)row * 512 + t];
    xs[t + 256] = x[(size_t)row * 512 + t + 256];
    hs[t]       = h[(size_t)row * 512 + t];
    hs[t + 256] = h[(size_t)row * 512 + t + 256];
    __syncthreads();
    float p0 = 0.f, p1 = 0.f;
    for (int jj = 0; jj < 2; ++jj) {
        const int j = t + jj * 256;
        float af = bfp[j], ai = bip[j], ao = bop[j], ac = bcp[j];
        for (int k = 0; k < 512; ++k) {
            float xv = xs[k], hv = hs[k];
            af += xv * Uf[k * 512 + j] + hv * Vf[k * 512 + j];
            ai += xv * Ui[k * 512 + j] + hv * Vi[k * 512 + j];
            ao += xv * Uo[k * 512 + j] + hv * Vo[k * 512 + j];
            ac += xv * Uc[k * 512 + j] + hv * Vc[k * 512 + j];
        }
        float gf = 1.f / (1.f + __expf(-af));
        float gi = 1.f / (1.f + __expf(-ai));
        float go = 1.f / (1.f + __expf(-ao));
        float ch = tanhf(ac);
        float cold = cell[(size_t)row * 512 + j];
        float cn = gf * cold + gi * ch;
        float hn = go * tanhf(cn);
        out[65536 + (size_t)row * 512 + j]            = hn;
        out[65536 + 16777216 + (size_t)row * 512 + j] = cn;
        p0 += hn * Wout[j * 2 + 0];
        p1 += hn * Wout[j * 2 + 1];
    }
    #pragma unroll
    for (int off = 32; off > 0; off >>= 1) {
        p0 += __shfl_down(p0, off);
        p1 += __shfl_down(p1, off);
    }
    __shared__ float r0[4], r1[4];
    if ((t & 63) == 0) { r0[t >> 6] = p0; r1[t >> 6] = p1; }
    __syncthreads();
    if (t == 0) {
        float l0 = r0[0] + r0[1] + r0[2] + r0[3] + bout[0];
        float l1 = r1[0] + r1[1] + r1[2] + r1[3] + bout[1];
        float mx = fmaxf(l0, l1);
        float e0 = __expf(l0 - mx), e1 = __expf(l1 - mx);
        float s  = e0 + e1;
        out[(size_t)row * 2 + 0] = e0 / s;
        out[(size_t)row * 2 + 1] = e1 / s;
    }
}

extern "C" void kernel_launch(void* const* d_in, const int* in_sizes, int n_in,
                              void* d_out, int out_size, void* d_ws, size_t ws_size,
                              hipStream_t stream) {
    const float* x    = (const float*)d_in[0];
    const float* h    = (const float*)d_in[1];
    const float* c    = (const float*)d_in[2];
    const float* Uf   = (const float*)d_in[3];
    const float* Vf   = (const float*)d_in[4];
    const float* bfp  = (const float*)d_in[5];
    const float* Ui   = (const float*)d_in[6];
    const float* Vi   = (const float*)d_in[7];
    const float* bip  = (const float*)d_in[8];
    const float* Uo   = (const float*)d_in[9];
    const float* Vo   = (const float*)d_in[10];
    const float* bop  = (const float*)d_in[11];
    const float* Uc   = (const float*)d_in[12];
    const float* Vc   = (const float*)d_in[13];
    const float* bcp  = (const float*)d_in[14];
    const float* Wout = (const float*)d_in[15];
    const float* bout = (const float*)d_in[16];
    float* out = (float*)d_out;

    const size_t needXH  = (size_t)B_ * K_ * 2;   // 64 MB
    const size_t needWt  = (size_t)2048 * K_ * 2; //  4 MB
    const size_t needAcc = (size_t)B_ * 2 * 4;    // 256 KB

    if (ws_size >= needXH + needWt + needAcc) {
        unsigned short* XHt  = (unsigned short*)d_ws;
        unsigned short* Wtt  = (unsigned short*)((char*)d_ws + needXH);
        float*          accL = (float*)((char*)d_ws + needXH + needWt);

        prep_kernel<<<16384 + 2048 + 16, 256, 0, stream>>>(
            x, h, Uf, Vf, Ui, Vi, Uo, Vo, Uc, Vc, XHt, Wtt, accL);
        gemm_fused_kernel<<<dim3(16, 256), 256, 0, stream>>>(
            XHt, Wtt, c, bfp, bip, bop, bcp, Wout, accL, out);
        finale_kernel<<<B_ / 256, 256, 0, stream>>>(accL, bout, out);
    } else {
        fallback_kernel<<<B_, 256, 0, stream>>>(x, h, c, Uf, Vf, bfp, Ui, Vi, bip,
                                                Uo, Vo, bop, Uc, Vc, bcp, Wout, bout, out);
    }
}

// Round 6
// 449.968 us; speedup vs baseline: 1.0171x; 1.0171x over previous
//
#include <hip/hip_runtime.h>
#include <math.h>

#define B_   32768
#define K_   1024
#define NIT  32          // K-loop iterations (BK = 32)
#define CPT  512         // 16B chunks per operand per iter-tile: 128 rows x 4 col-chunks
#define BUFS 8192        // shorts per buffer (16 KB): A-half + B-half

typedef __bf16 bf16x8 __attribute__((ext_vector_type(8)));
typedef float  f32x4  __attribute__((ext_vector_type(4)));
typedef float  f4     __attribute__((ext_vector_type(4)));
typedef float  f2     __attribute__((ext_vector_type(2)));
typedef unsigned short us8 __attribute__((ext_vector_type(8)));

__device__ __forceinline__ unsigned short f2bf(float f) {
    unsigned u = __float_as_uint(f);
    u += 0x7fffu + ((u >> 16) & 1u);   // round-to-nearest-even
    return (unsigned short)(u >> 16);
}
__device__ __forceinline__ float sigm(float x) {
    return 1.f / (1.f + __expf(-x));
}
__device__ __forceinline__ float tanh_fast(float x) {
    return 1.f - 2.f / (__expf(2.f * x) + 1.f);
}
// async global->LDS, 16B per lane. LDS dest = wave-uniform base + lane*16.
__device__ __forceinline__ void gload16(const unsigned short* g, unsigned short* l) {
    __builtin_amdgcn_global_load_lds(
        (const __attribute__((address_space(1))) unsigned int*)g,
        (__attribute__((address_space(3))) unsigned int*)l, 16, 0, 0);
}

// ---------------- prep: pack x||h -> XHt, transpose-pack weights -> Wtt, zero accL ----
// Role by blockIdx.x (all branches block-uniform):
//   [0, 16384)        : XHt chunks (tiled + pre-swizzled)
//   [16384, 18432)    : Wtt tiles  (tiled + pre-swizzled)
//   [18432, 18448)    : zero the 256 KB logit accumulator
__global__ __launch_bounds__(256) void prep_kernel(
    const float* __restrict__ x, const float* __restrict__ h,
    const float* __restrict__ Uf, const float* __restrict__ Vf,
    const float* __restrict__ Ui, const float* __restrict__ Vi,
    const float* __restrict__ Uo, const float* __restrict__ Vo,
    const float* __restrict__ Uc, const float* __restrict__ Vc,
    unsigned short* __restrict__ XHt, unsigned short* __restrict__ Wtt,
    float* __restrict__ accL) {
    __shared__ float tile[32][33];
    const int b = blockIdx.x;
    const int t = threadIdx.x;
    if (b < 16384) {
        // XHt chunk p = (mb*32 + it)*512 + r*4 + gcx holds 8 bf16 of
        // XH[mb*128 + r][it*32 + (gcx ^ ((r>>1)&3))*8 .. +7]  (k<512 -> x, else h)
        unsigned p   = b * 256u + t;
        unsigned c   = p & 511u;
        unsigned T   = p >> 9;
        unsigned it  = T & 31u;
        unsigned mb  = T >> 5;
        unsigned r   = c >> 2;
        unsigned gcx = c & 3u;
        unsigned gc  = gcx ^ ((r >> 1) & 3u);
        unsigned m   = mb * 128u + r;
        unsigned k   = it * 32u + gc * 8u;
        const float* src = (k < 512u) ? (x + (size_t)m * 512u + k)
                                      : (h + (size_t)m * 512u + (k - 512u));
        f4 v0 = *(const f4*)src;
        f4 v1 = *(const f4*)(src + 4);
        us8 o;
        o[0] = f2bf(v0.x); o[1] = f2bf(v0.y); o[2] = f2bf(v0.z); o[3] = f2bf(v0.w);
        o[4] = f2bf(v1.x); o[5] = f2bf(v1.y); o[6] = f2bf(v1.z); o[7] = f2bf(v1.w);
        *(us8*)(XHt + (size_t)p * 8u) = o;
    } else if (b < 18432) {
        // Wtt chunk p = (jb*32 + it)*512 + r*4 + gcx, r = g*32 + jj, holds
        // W[row = g*512 + jb*32 + jj][k = it*32 + (gcx^((jj>>1)&3))*8 .. +7]
        const float* srcs[8] = {Uf, Vf, Ui, Vi, Uo, Vo, Uc, Vc};
        const int idx = b - 16384;           // 0..2047
        const int w   = idx >> 8;            // 0..7 : (g, isV)
        const int kw  = (idx >> 4) & 15;     // 32-k window within the 512
        const int jb  = idx & 15;
        const float* src = srcs[w];
        const int g   = w >> 1;
        const int isV = w & 1;
        const int j0  = jb * 32;
        const int k0  = kw * 32;
        const int it  = isV * 16 + kw;
        #pragma unroll
        for (int p = 0; p < 4; ++p) {
            int kl = p * 8 + (t >> 5);
            int jj = t & 31;
            tile[kl][jj] = src[(size_t)(k0 + kl) * 512 + j0 + jj];   // coalesced over j
        }
        __syncthreads();
        if (t < 128) {
            const int jj  = t >> 2;
            const int gcx = t & 3;
            const int gc  = gcx ^ ((jj >> 1) & 3);
            const int r   = g * 32 + jj;
            us8 o;
            #pragma unroll
            for (int u = 0; u < 8; ++u) o[u] = f2bf(tile[gc * 8 + u][jj]);
            *(us8*)(Wtt + ((size_t)(jb * 32 + it) * 512 + r * 4 + gcx) * 8) = o;
        }
    } else {
        // zero accL: 65536 floats; 16 blocks x 256 threads x 16B
        const int i = (b - 18432) * 256 + t;
        f4 z = {0.f, 0.f, 0.f, 0.f};
        *(f4*)(accL + (size_t)i * 4) = z;
    }
}

// ---------------- fused GEMM + LSTM gates + partial logits ----------------
// 128x128 output tile (128 rows x {4 gates x 32 j}), BK=32, 4 waves, 16x16x32 MFMA.
// K-loop: 3-buffer LDS ring, ONE raw s_barrier per iteration, COUNTED vmcnt(4)
// (T4: never drain to 0 in the main loop; stage(X+1)'s DMAs stay in flight
// across the barrier). Body: vmcnt(4) -> s_barrier -> stage(X+2) -> compute(X).
// Each wave's own vmcnt(4) guarantees its stage(X) writes landed before it
// arrives at the barrier; the barrier also orders stage(X+2)'s overwrite of
// buf (X-1)%3 after all compute(X-1) readers. Last iteration peels to vmcnt(0).
// Sources tiled+pre-swizzled so LDS stays linear and fragment ds_read_b128 are
// conflict-free (validated r4: FETCH 204MB, WRITE = exact output bytes).
__global__ __launch_bounds__(256, 2) void gemm_fused_kernel(
    const unsigned short* __restrict__ XHt,
    const unsigned short* __restrict__ Wtt,
    const float* __restrict__ cell,
    const float* __restrict__ bfp, const float* __restrict__ bip,
    const float* __restrict__ bop, const float* __restrict__ bcp,
    const float* __restrict__ Wout,
    float* __restrict__ accL,
    float* __restrict__ out) {
    __shared__ __attribute__((aligned(16))) unsigned short lds[3 * BUFS];  // 48 KB
    const int t    = threadIdx.x;
    const int lane = t & 63;
    const int w    = t >> 6;
    const int wm   = w >> 1;
    const int wn   = w & 1;

    // XCD swizzle (bijective, 4096 % 8 == 0): each XCD gets contiguous m-strips
    // with jb fastest -> XH strip reuse in that XCD's L2.
    const unsigned lin = blockIdx.y * gridDim.x + blockIdx.x;
    const unsigned wg  = (lin & 7u) * 512u + (lin >> 3);
    const int jb = (int)(wg & 15u);
    const int mb = (int)(wg >> 4);
    const int jblk = jb * 32;
    const int m0   = mb * 128;

    f32x4 acc[4][4];
    #pragma unroll
    for (int i = 0; i < 4; ++i)
        #pragma unroll
        for (int j = 0; j < 4; ++j) { f32x4 z = {0.f, 0.f, 0.f, 0.f}; acc[i][j] = z; }

    const unsigned short* aS = XHt + (size_t)mb * (NIT * CPT * 8);
    const unsigned short* bS = Wtt + (size_t)jb * (NIT * CPT * 8);
    const int cw = w * 64;                 // wave's chunk base within a 256-chunk group

    auto stage = [&](int buf, int it) {
        const unsigned short* a = aS + (size_t)it * (CPT * 8);
        const unsigned short* b = bS + (size_t)it * (CPT * 8);
        unsigned short* lA = lds + buf * BUFS;
        unsigned short* lB = lA + CPT * 8;
        gload16(a + (size_t)(cw + lane) * 8,       lA + cw * 8);
        gload16(a + (size_t)(cw + lane + 256) * 8, lA + (cw + 256) * 8);
        gload16(b + (size_t)(cw + lane) * 8,       lB + cw * 8);
        gload16(b + (size_t)(cw + lane + 256) * 8, lB + (cw + 256) * 8);
    };

    const int q   = lane & 15;
    const int ccf = lane >> 4;                  // k-chunk of the fragment
    const int swz = ccf ^ ((q >> 1) & 3);       // (r>>1)&3 == (q>>1)&3 for all our rows

    auto compute = [&](int buf) {
        const unsigned short* lA = lds + buf * BUFS;
        const unsigned short* lB = lA + CPT * 8;
        bf16x8 af[4], bfr[4];
        #pragma unroll
        for (int mt = 0; mt < 4; ++mt)
            af[mt] = *(const bf16x8*)(lA + ((wm * 64 + mt * 16 + q) * 4 + swz) * 8);
        #pragma unroll
        for (int nt = 0; nt < 4; ++nt)
            bfr[nt] = *(const bf16x8*)(lB + ((nt * 32 + wn * 16 + q) * 4 + swz) * 8);
        #pragma unroll
        for (int mt = 0; mt < 4; ++mt)
            #pragma unroll
            for (int nt = 0; nt < 4; ++nt)
                acc[mt][nt] = __builtin_amdgcn_mfma_f32_16x16x32_bf16(af[mt], bfr[nt], acc[mt][nt], 0, 0, 0);
    };

    stage(0, 0);
    stage(1, 1);
    int bufX = 0;
    for (int X = 0; X < NIT; ++X) {
        __builtin_amdgcn_sched_barrier(0);
        if (X < NIT - 1) {
            asm volatile("s_waitcnt vmcnt(4)" ::: "memory");   // stage(X) landed; stage(X+1) in flight
        } else {
            asm volatile("s_waitcnt vmcnt(0)" ::: "memory");   // final tile: full drain
        }
        __builtin_amdgcn_s_barrier();                          // raw: no implicit vmcnt drain
        __builtin_amdgcn_sched_barrier(0);
        if (X + 2 < NIT) {
            int b2 = bufX + 2; if (b2 >= 3) b2 -= 3;
            stage(b2, X + 2);                                  // in flight through compute(X)+
        }
        compute(bufX);
        if (++bufX == 3) bufX = 0;
    }

    // ---- fused epilogue ----
    // C/D layout: col = lane&15 (-> local j), row = (lane>>4)*4 + rr; nt = gate.
    const int jc  = wn * 16 + q;               // local col in [0,32)
    const int j   = jblk + jc;                 // global hidden idx
    const float bF = bfp[j], bI = bip[j], bO = bop[j], bC = bcp[j];
    const int rlb = wm * 64 + ((lane >> 4) << 2);
    float hnv[16], cnv[16];
    #pragma unroll
    for (int mt = 0; mt < 4; ++mt) {
        #pragma unroll
        for (int rr = 0; rr < 4; ++rr) {
            const int row = m0 + rlb + mt * 16 + rr;
            const float sf = sigm(acc[mt][0][rr] + bF);
            const float si = sigm(acc[mt][1][rr] + bI);
            const float so = sigm(acc[mt][2][rr] + bO);
            const float ch = tanh_fast(acc[mt][3][rr] + bC);
            const float cold = cell[(size_t)row * 512 + j];
            const float cn = sf * cold + si * ch;
            cnv[mt * 4 + rr] = cn;
            hnv[mt * 4 + rr] = so * tanh_fast(cn);
        }
    }

    __syncthreads();    // all waves done with the K-loop LDS before reuse as eb

    // LDS-staged full-128B-line stores. 128 x 36-padded f32 tile = 18.4 KB.
    float* eb   = (float*)lds;
    float* hout = out + 65536;
    float* cout = out + 65536 + 16777216;
    #pragma unroll
    for (int mt = 0; mt < 4; ++mt)
        #pragma unroll
        for (int rr = 0; rr < 4; ++rr)
            eb[(rlb + mt * 16 + rr) * 36 + jc] = hnv[mt * 4 + rr];
    __syncthreads();
    #pragma unroll
    for (int i = 0; i < 4; ++i) {   // each wave-instr: 64 lanes x 16B = 8 full lines
        const int r  = i * 32 + (t >> 3);
        const int c4 = (t & 7) * 4;
        f4 v = *(const f4*)(eb + r * 36 + c4);
        *(f4*)(hout + (size_t)(m0 + r) * 512 + jblk + c4) = v;
    }
    // partial logits from the h tile still in LDS: 2 threads/row, 16 cols each
    {
        const int r    = t >> 1;           // 0..127
        const int half = t & 1;
        const int c0   = half * 16;
        float p0 = 0.f, p1 = 0.f;
        #pragma unroll
        for (int i = 0; i < 16; ++i) {
            const float hv = eb[r * 36 + c0 + i];
            const float w0 = Wout[(jblk + c0 + i) * 2 + 0];
            const float w1 = Wout[(jblk + c0 + i) * 2 + 1];
            p0 += hv * w0;
            p1 += hv * w1;
        }
        p0 += __shfl_xor(p0, 1);           // combine the two halves of the row
        p1 += __shfl_xor(p1, 1);
        if (half == 0) {
            atomicAdd(&accL[(size_t)(m0 + r) * 2 + 0], p0);
            atomicAdd(&accL[(size_t)(m0 + r) * 2 + 1], p1);
        }
    }
    __syncthreads();
    #pragma unroll
    for (int mt = 0; mt < 4; ++mt)
        #pragma unroll
        for (int rr = 0; rr < 4; ++rr)
            eb[(rlb + mt * 16 + rr) * 36 + jc] = cnv[mt * 4 + rr];
    __syncthreads();
    #pragma unroll
    for (int i = 0; i < 4; ++i) {
        const int r  = i * 32 + (t >> 3);
        const int c4 = (t & 7) * 4;
        f4 v = *(const f4*)(eb + r * 36 + c4);
        *(f4*)(cout + (size_t)(m0 + r) * 512 + jblk + c4) = v;
    }
}

// ---------------- finale: softmax over accumulated logits ----------------
__global__ __launch_bounds__(256) void finale_kernel(const float* __restrict__ accL,
                                                     const float* __restrict__ bout,
                                                     float* __restrict__ out) {
    const int row = blockIdx.x * 256 + threadIdx.x;
    f2 a = *(const f2*)(accL + (size_t)row * 2);
    float l0 = a.x + bout[0], l1 = a.y + bout[1];
    float mx = fmaxf(l0, l1);
    float e0 = __expf(l0 - mx), e1 = __expf(l1 - mx);
    float s  = e0 + e1;
    f2 r; r.x = e0 / s; r.y = e1 / s;
    *(f2*)(out + (size_t)row * 2) = r;
}

// ---------------- fallback (only if workspace is too small): naive fp32 ----------------
__global__ __launch_bounds__(256) void fallback_kernel(
    const float* __restrict__ x, const float* __restrict__ h, const float* __restrict__ cell,
    const float* __restrict__ Uf, const float* __restrict__ Vf, const float* __restrict__ bfp,
    const float* __restrict__ Ui, const float* __restrict__ Vi, const float* __restrict__ bip,
    const float* __restrict__ Uo, const float* __restrict__ Vo, const float* __restrict__ bop,
    const float* __restrict__ Uc, const float* __restrict__ Vc, const float* __restrict__ bcp,
    const float* __restrict__ Wout, const float* __restrict__ bout, float* __restrict__ out) {
    const int row = blockIdx.x;
    const int t   = threadIdx.x;
    __shared__ float xs[512], hs[512];
    xs[t]       = x[(size_t)row * 512 + t];
    xs[t + 256] = x[(size_t)row * 512 + t + 256];
    hs[t]       = h[(size_t)row * 512 + t];
    hs[t + 256] = h[(size_t)row * 512 + t + 256];
    __syncthreads();
    float p0 = 0.f, p1 = 0.f;
    for (int jj = 0; jj < 2; ++jj) {
        const int j = t + jj * 256;
        float af = bfp[j], ai = bip[j], ao = bop[j], ac = bcp[j];
        for (int k = 0; k < 512; ++k) {
            float xv = xs[k], hv = hs[k];
            af += xv * Uf[k * 512 + j] + hv * Vf[k * 512 + j];
            ai += xv * Ui[k * 512 + j] + hv * Vi[k * 512 + j];
            ao += xv * Uo[k * 512 + j] + hv * Vo[k * 512 + j];
            ac += xv * Uc[k * 512 + j] + hv * Vc[k * 512 + j];
        }
        float gf = 1.f / (1.f + __expf(-af));
        float gi = 1.f / (1.f + __expf(-ai));
        float go = 1.f / (1.f + __expf(-ao));
        float ch = tanhf(ac);
        float cold = cell[(size_t)row * 512 + j];
        float cn = gf * cold + gi * ch;
        float hn = go * tanhf(cn);
        out[65536 + (size_t)row * 512 + j]            = hn;
        out[65536 + 16777216 + (size_t)row * 512 + j] = cn;
        p0 += hn * Wout[j * 2 + 0];
        p1 += hn * Wout[j * 2 + 1];
    }
    #pragma unroll
    for (int off = 32; off > 0; off >>= 1) {
        p0 += __shfl_down(p0, off);
        p1 += __shfl_down(p1, off);
    }
    __shared__ float r0[4], r1[4];
    if ((t & 63) == 0) { r0[t >> 6] = p0; r1[t >> 6] = p1; }
    __syncthreads();
    if (t == 0) {
        float l0 = r0[0] + r0[1] + r0[2] + r0[3] + bout[0];
        float l1 = r1[0] + r1[1] + r1[2] + r1[3] + bout[1];
        float mx = fmaxf(l0, l1);
        float e0 = __expf(l0 - mx), e1 = __expf(l1 - mx);
        float s  = e0 + e1;
        out[(size_t)row * 2 + 0] = e0 / s;
        out[(size_t)row * 2 + 1] = e1 / s;
    }
}

extern "C" void kernel_launch(void* const* d_in, const int* in_sizes, int n_in,
                              void* d_out, int out_size, void* d_ws, size_t ws_size,
                              hipStream_t stream) {
    const float* x    = (const float*)d_in[0];
    const float* h    = (const float*)d_in[1];
    const float* c    = (const float*)d_in[2];
    const float* Uf   = (const float*)d_in[3];
    const float* Vf   = (const float*)d_in[4];
    const float* bfp  = (const float*)d_in[5];
    const float* Ui   = (const float*)d_in[6];
    const float* Vi   = (const float*)d_in[7];
    const float* bip  = (const float*)d_in[8];
    const float* Uo   = (const float*)d_in[9];
    const float* Vo   = (const float*)d_in[10];
    const float* bop  = (const float*)d_in[11];
    const float* Uc   = (const float*)d_in[12];
    const float* Vc   = (const float*)d_in[13];
    const float* bcp  = (const float*)d_in[14];
    const float* Wout = (const float*)d_in[15];
    const float* bout = (const float*)d_in[16];
    float* out = (float*)d_out;

    const size_t needXH  = (size_t)B_ * K_ * 2;   // 64 MB
    const size_t needWt  = (size_t)2048 * K_ * 2; //  4 MB
    const size_t needAcc = (size_t)B_ * 2 * 4;    // 256 KB

    if (ws_size >= needXH + needWt + needAcc) {
        unsigned short* XHt  = (unsigned short*)d_ws;
        unsigned short* Wtt  = (unsigned short*)((char*)d_ws + needXH);
        float*          accL = (float*)((char*)d_ws + needXH + needWt);

        prep_kernel<<<16384 + 2048 + 16, 256, 0, stream>>>(
            x, h, Uf, Vf, Ui, Vi, Uo, Vo, Uc, Vc, XHt, Wtt, accL);
        gemm_fused_kernel<<<dim3(16, 256), 256, 0, stream>>>(
            XHt, Wtt, c, bfp, bip, bop, bcp, Wout, accL, out);
        finale_kernel<<<B_ / 256, 256, 0, stream>>>(accL, bout, out);
    } else {
        fallback_kernel<<<B_, 256, 0, stream>>>(x, h, c, Uf, Vf, bfp, Ui, Vi, bip,
                                                Uo, Vo, bop, Uc, Vc, bcp, Wout, bout, out);
    }
}